// Round 13
// baseline (814.007 us; speedup 1.0000x reference)
//
#include <hip/hip_runtime.h>

#define NN 50000
#define NE 800000
#define HID 128
#define OUTC 64
#define NG 128
#define NLAY 3
#define BN_EPS 1e-5f
#define NBKT 196          // ceil(NN/256) buckets of 256 nodes
#define NPB 256           // partition blocks
#define EPB ((NE + NPB - 1) / NPB)
#define LCAP 8192

typedef __attribute__((ext_vector_type(8))) short bfrag;
typedef __attribute__((ext_vector_type(4))) float f4;

__device__ __forceinline__ ushort f2b(float f) {
    union { float f; unsigned u; } x; x.f = f;
    unsigned u = x.u;
    unsigned r = (u + 0x7fffu + ((u >> 16) & 1u)) >> 16;  // RNE
    return (ushort)r;
}
__device__ __forceinline__ float b2f(ushort b) {
    union { unsigned u; float f; } x; x.u = ((unsigned)b) << 16; return x.f;
}

// ---- weight prep + buffer init -------------------------------------------
__global__ void k_prep(const float* __restrict__ lin_w, const float* __restrict__ rel_w,
                       const float* __restrict__ root_w, const float* __restrict__ rel_l,
                       const float* __restrict__ root_l, ushort* __restrict__ wT,
                       float* __restrict__ aff, float* __restrict__ bn_sh,
                       float* __restrict__ out, int* __restrict__ cnt) {
    int idx = blockIdx.x * 256 + threadIdx.x;
    if (idx < 7 * 16384) {
        int m = idx >> 14, r = idx & 16383;
        int n = r >> 7, k = r & 127;
        const float* src = (m == 0) ? lin_w
                         : (m <= 3 ? rel_w + (m - 1) * 16384 : root_w + (m - 4) * 16384);
        wT[idx] = f2b(src[k * 128 + n]);
    } else {
        int r = idx - 7 * 16384;
        int m = r >> 13, rr = r & 8191;
        int n = rr >> 7, k = rr & 127;
        const float* src = m ? root_l : rel_l;
        wT[idx] = f2b(src[k * 64 + n]);
    }
    if (idx < 128) aff[idx] = 1.0f;                 // layer-0 identity scale
    else if (idx < 256) aff[idx] = 0.0f;            // layer-0 zero shift
    if (idx < NG * OUTC) out[idx] = 0.0f;
    if (idx < NLAY * 64 * 256) bn_sh[idx] = 0.0f;
    if (idx < NLAY) cnt[idx] = 0;
}

// ---- CSR build via bucketed counting sort (LDS atomics only) --------------
__global__ __launch_bounds__(256) void k_part1(const int* __restrict__ ei,
                                               int* __restrict__ p_hist) {
    __shared__ int hist[NBKT];
    int t = threadIdx.x;
    if (t < NBKT) hist[t] = 0;
    __syncthreads();
    int e0 = blockIdx.x * EPB, e1 = min(e0 + EPB, NE);
    for (int e = e0 + t; e < e1; e += 256)
        atomicAdd(&hist[ei[NE + e] >> 8], 1);
    __syncthreads();
    if (t < NBKT) p_hist[blockIdx.x * NBKT + t] = hist[t];
}

__global__ void k_part2a(int* __restrict__ p_hist, int* __restrict__ btot) {
    __shared__ int s[256];
    int k = blockIdx.x, t = threadIdx.x;
    int v = p_hist[t * NBKT + k];
    s[t] = v;
    __syncthreads();
    for (int d = 1; d < 256; d <<= 1) {
        int u = 0;
        if (t >= d) u = s[t - d];
        __syncthreads();
        s[t] += u;
        __syncthreads();
    }
    p_hist[t * NBKT + k] = s[t] - v;   // exclusive over blocks
    if (t == 255) btot[k] = s[255];
}

__global__ void k_part2b(const int* __restrict__ btot, int* __restrict__ bstart,
                         int* __restrict__ offs) {
    __shared__ int s[256];
    int t = threadIdx.x;
    int v = (t < NBKT) ? btot[t] : 0;
    s[t] = v;
    __syncthreads();
    for (int d = 1; d < 256; d <<= 1) {
        int u = 0;
        if (t >= d) u = s[t - d];
        __syncthreads();
        s[t] += u;
        __syncthreads();
    }
    if (t < NBKT) bstart[t] = s[t] - v;
    if (t == 0) { bstart[NBKT] = NE; offs[NN] = NE; }
}

__global__ __launch_bounds__(256) void k_part3(const int* __restrict__ ei,
                                               const int* __restrict__ p_hist,
                                               const int* __restrict__ bstart,
                                               unsigned* __restrict__ epk) {
    __shared__ int cur[NBKT];
    int t = threadIdx.x;
    if (t < NBKT) cur[t] = p_hist[blockIdx.x * NBKT + t] + bstart[t];
    __syncthreads();
    int e0 = blockIdx.x * EPB, e1 = min(e0 + EPB, NE);
    for (int e = e0 + t; e < e1; e += 256) {
        int d = ei[NE + e], s = ei[e];
        int p = atomicAdd(&cur[d >> 8], 1);
        epk[p] = (unsigned)s | ((unsigned)(d & 255) << 16);
    }
}

__global__ __launch_bounds__(256) void k_csr(const unsigned* __restrict__ epk,
                                             const int* __restrict__ bstart,
                                             ushort* __restrict__ csr,
                                             int* __restrict__ offs) {
    __shared__ int cnt[256];
    __shared__ int cur[256];
    __shared__ ushort lcsr[LCAP];
    int b = blockIdx.x, t = threadIdx.x;
    int e0 = bstart[b], e1 = bstart[b + 1];
    int sz = e1 - e0;
    cnt[t] = 0;
    __syncthreads();
    for (int i = t; i < sz; i += 256)
        atomicAdd(&cnt[epk[e0 + i] >> 16], 1);
    __syncthreads();
    int v = cnt[t];
    for (int d = 1; d < 256; d <<= 1) {
        int u = 0;
        if (t >= d) u = cnt[t - d];
        __syncthreads();
        cnt[t] += u;
        __syncthreads();
    }
    int excl = cnt[t] - v;
    cur[t] = excl;
    int node = b * 256 + t;
    if (node < NN) offs[node] = e0 + excl;
    __syncthreads();
    for (int i = t; i < sz; i += 256) {
        unsigned pk = epk[e0 + i];
        int p = atomicAdd(&cur[pk >> 16], 1);
        lcsr[p] = (ushort)(pk & 0xffffu);
    }
    __syncthreads();
    for (int i = t; i < sz; i += 256) csr[e0 + i] = lcsr[i];
}

// ---- initial linear: h = bf16(x @ lin_w + lin_b) --------------------------
__global__ __launch_bounds__(256) void k_lin(const float* __restrict__ x,
                                             const ushort* __restrict__ wT,
                                             const float* __restrict__ bias,
                                             ushort* __restrict__ h) {
    __shared__ __align__(16) ushort tp[4][16 * 136];
    int t = threadIdx.x;
    int lane = t & 63, wv = t >> 6;
    int node0 = (blockIdx.x * 4 + wv) * 16;
    int l15 = lane & 15, q = lane >> 4;
    int nA = min(node0 + l15, NN - 1);
    f4 acc[8];
#pragma unroll
    for (int nt = 0; nt < 8; nt++) acc[nt] = (f4)0.0f;
#pragma unroll
    for (int ks = 0; ks < 4; ks++) {
        const float* ap = x + (size_t)nA * HID + ks * 32 + q * 8;
        f4 x0 = *(const f4*)ap;
        f4 x1 = *(const f4*)(ap + 4);
        bfrag a;
#pragma unroll
        for (int j = 0; j < 4; j++) { a[j] = (short)f2b(x0[j]); a[4 + j] = (short)f2b(x1[j]); }
#pragma unroll
        for (int nt = 0; nt < 8; nt++) {
            bfrag b = *(const bfrag*)(wT + (nt * 16 + l15) * HID + ks * 32 + q * 8);
            acc[nt] = __builtin_amdgcn_mfma_f32_16x16x32_bf16(a, b, acc[nt], 0, 0, 0);
        }
    }
#pragma unroll
    for (int nt = 0; nt < 8; nt++) {
        float bs = bias[nt * 16 + l15];
#pragma unroll
        for (int r = 0; r < 4; r++)
            tp[wv][(q * 4 + r) * 136 + nt * 16 + l15] = f2b(acc[nt][r] + bs);
    }
    __syncthreads();
#pragma unroll
    for (int i = 0; i < 4; i++) {
        int nr = node0 + i * 4 + q;
        if (nr < NN) {
            bfrag tv = *(const bfrag*)&tp[wv][(i * 4 + q) * 136 + l15 * 8];
            *(bfrag*)(h + (size_t)nr * HID + l15 * 8) = tv;
        }
    }
}

// ---- aggregation with fused BN+relu (r5/r7/r9 proven form) ----------------
__global__ __launch_bounds__(256) void k_agg(const ushort* __restrict__ hb,
                                             const int* __restrict__ offs,
                                             const ushort* __restrict__ csr,
                                             const float* __restrict__ aff,
                                             float negk,
                                             ushort* __restrict__ agg) {
    int gw = (blockIdx.x * 256 + threadIdx.x) >> 6;  // one wave per node
    int lane = threadIdx.x & 63;
    int slot = lane >> 4, c16 = lane & 15;
    if (gw >= NN) return;
    float scv[8], shv[8];
    *(f4*)&scv[0] = *(const f4*)(aff + c16 * 8);
    *(f4*)&scv[4] = *(const f4*)(aff + c16 * 8 + 4);
    *(f4*)&shv[0] = *(const f4*)(aff + 128 + c16 * 8);
    *(f4*)&shv[4] = *(const f4*)(aff + 128 + c16 * 8 + 4);
    int e0 = offs[gw], e1 = offs[gw + 1];
    float a[8];
#pragma unroll
    for (int j = 0; j < 8; j++) a[j] = 0.f;
    int base = e0;
    for (; base + 8 <= e1; base += 8) {
        int s0 = csr[base + slot];
        int s1 = csr[base + 4 + slot];
        bfrag v0 = *(const bfrag*)(hb + (size_t)s0 * HID + c16 * 8);
        bfrag v1 = *(const bfrag*)(hb + (size_t)s1 * HID + c16 * 8);
#pragma unroll
        for (int j = 0; j < 8; j++) {
            float t0 = b2f((ushort)v0[j]) * scv[j] + shv[j];
            float t1 = b2f((ushort)v1[j]) * scv[j] + shv[j];
            a[j] += fmaxf(t0, t0 * negk) + fmaxf(t1, t1 * negk);
        }
    }
    if (base + 4 <= e1) {
        int s0 = csr[base + slot];
        bfrag v0 = *(const bfrag*)(hb + (size_t)s0 * HID + c16 * 8);
#pragma unroll
        for (int j = 0; j < 8; j++) {
            float t0 = b2f((ushort)v0[j]) * scv[j] + shv[j];
            a[j] += fmaxf(t0, t0 * negk);
        }
        base += 4;
    }
    int rem = e1 - base;
    if (slot < rem) {
        int s0 = csr[base + slot];
        bfrag v0 = *(const bfrag*)(hb + (size_t)s0 * HID + c16 * 8);
#pragma unroll
        for (int j = 0; j < 8; j++) {
            float t0 = b2f((ushort)v0[j]) * scv[j] + shv[j];
            a[j] += fmaxf(t0, t0 * negk);
        }
    }
#pragma unroll
    for (int j = 0; j < 8; j++) {
        a[j] += __shfl_xor(a[j], 16);
        a[j] += __shfl_xor(a[j], 32);
    }
    if (slot == 0) {
        bfrag o;
#pragma unroll
        for (int j = 0; j < 8; j++) o[j] = (short)f2b(a[j]);
        *(bfrag*)(agg + (size_t)gw * HID + c16 * 8) = o;
    }
}

// ---- conv layer: 32 nodes/block, N-split x2 (r9) + last-block BN finalize -
__global__ __launch_bounds__(256) void k_conv(const ushort* __restrict__ agg,
                                              const ushort* __restrict__ hb,
                                              const ushort* __restrict__ relT,
                                              const ushort* __restrict__ rootT,
                                              const float* __restrict__ bias,
                                              const float* __restrict__ aff,
                                              float negk,
                                              float* __restrict__ bn_sh,
                                              ushort* __restrict__ h2,
                                              const float* __restrict__ gamma,
                                              const float* __restrict__ beta,
                                              float* __restrict__ aff_out,
                                              int* __restrict__ counter) {
    __shared__ __align__(16) ushort tp[32 * 136];     // conv result (pre-residual)
    __shared__ __align__(16) ushort rtile[32 * 136];  // BN'd root rows
    __shared__ float lsum[256];
    __shared__ float lsc[128], lsh[128];
    __shared__ int isLast;
    int t = threadIdx.x;
    lsum[t] = 0.f;
    if (t < 128) { lsc[t] = aff[t]; lsh[t] = aff[128 + t]; }
    int lane = t & 63, wv = t >> 6;
    int ng = wv & 1, nh = wv >> 1;    // node-group, channel-half
    int l15 = lane & 15, q = lane >> 4;
    int node0 = blockIdx.x * 32 + ng * 16;
    int nA = min(node0 + l15, NN - 1);
    bfrag a1v[4], a2rv[4];
#pragma unroll
    for (int ks = 0; ks < 4; ks++) {
        a1v[ks] = *(const bfrag*)(agg + (size_t)nA * HID + ks * 32 + q * 8);
        a2rv[ks] = *(const bfrag*)(hb + (size_t)nA * HID + ks * 32 + q * 8);
    }
    __syncthreads();  // lsc/lsh + lsum init visible
    bfrag a2[4];
#pragma unroll
    for (int ks = 0; ks < 4; ks++) {
        float asc[8], ash[8];
        *(f4*)&asc[0] = *(const f4*)&lsc[ks * 32 + q * 8];
        *(f4*)&asc[4] = *(const f4*)&lsc[ks * 32 + q * 8 + 4];
        *(f4*)&ash[0] = *(const f4*)&lsh[ks * 32 + q * 8];
        *(f4*)&ash[4] = *(const f4*)&lsh[ks * 32 + q * 8 + 4];
#pragma unroll
        for (int j = 0; j < 8; j++) {
            float tt = b2f((ushort)a2rv[ks][j]) * asc[j] + ash[j];
            a2[ks][j] = (short)f2b(fmaxf(tt, tt * negk));
        }
        if (nh == 0)
            *(bfrag*)&rtile[(ng * 16 + l15) * 136 + ks * 32 + q * 8] = a2[ks];
    }
    f4 acc[4];
#pragma unroll
    for (int nt = 0; nt < 4; nt++) acc[nt] = (f4)0.0f;
#pragma unroll
    for (int ks = 0; ks < 4; ks++) {
#pragma unroll
        for (int nt = 0; nt < 4; nt++) {
            int ntg = nh * 4 + nt;
            bfrag b1 = *(const bfrag*)(relT + (ntg * 16 + l15) * HID + ks * 32 + q * 8);
            acc[nt] = __builtin_amdgcn_mfma_f32_16x16x32_bf16(a1v[ks], b1, acc[nt], 0, 0, 0);
            bfrag b2 = *(const bfrag*)(rootT + (ntg * 16 + l15) * HID + ks * 32 + q * 8);
            acc[nt] = __builtin_amdgcn_mfma_f32_16x16x32_bf16(a2[ks], b2, acc[nt], 0, 0, 0);
        }
    }
#pragma unroll
    for (int nt = 0; nt < 4; nt++) {
        int c = nh * 64 + nt * 16 + l15;
        float bs = bias[c];
#pragma unroll
        for (int r = 0; r < 4; r++)
            tp[(ng * 16 + q * 4 + r) * 136 + c] = f2b(acc[nt][r] + bs);
    }
    __syncthreads();
    // store path: thread = (row, 16-channel chunk)
    {
        int row = t >> 3, cb = (t & 7) * 16;
        int nr = blockIdx.x * 32 + row;
        if (nr < NN) {
            bfrag t0 = *(const bfrag*)&tp[row * 136 + cb];
            bfrag t1 = *(const bfrag*)&tp[row * 136 + cb + 8];
            bfrag r0 = *(const bfrag*)&rtile[row * 136 + cb];
            bfrag r1 = *(const bfrag*)&rtile[row * 136 + cb + 8];
            bfrag o0, o1;
#pragma unroll
            for (int j = 0; j < 8; j++) {
                o0[j] = (short)f2b(b2f((ushort)t0[j]) + b2f((ushort)r0[j]));
                o1[j] = (short)f2b(b2f((ushort)t1[j]) + b2f((ushort)r1[j]));
            }
            *(bfrag*)(h2 + (size_t)nr * HID + cb) = o0;
            *(bfrag*)(h2 + (size_t)nr * HID + cb + 8) = o1;
        }
    }
    // stats pass: wave wv covers rows wv*8..+8; lane covers channel pair (2l,2l+1)
    {
        float s0 = 0.f, s1 = 0.f, q0 = 0.f, q1 = 0.f;
        int c2 = lane * 2;
#pragma unroll
        for (int r = 0; r < 8; r++) {
            int row = wv * 8 + r;
            int nr = blockIdx.x * 32 + row;
            if (nr < NN) {
                unsigned tu = *(const unsigned*)&tp[row * 136 + c2];
                unsigned ru = *(const unsigned*)&rtile[row * 136 + c2];
                float v0 = b2f((ushort)(tu & 0xffffu)) + b2f((ushort)(ru & 0xffffu));
                float v1 = b2f((ushort)(tu >> 16)) + b2f((ushort)(ru >> 16));
                s0 += v0; s1 += v1; q0 += v0 * v0; q1 += v1 * v1;
            }
        }
        atomicAdd(&lsum[c2], s0);
        atomicAdd(&lsum[c2 + 1], s1);
        atomicAdd(&lsum[128 + c2], q0);
        atomicAdd(&lsum[128 + c2 + 1], q1);
    }
    __syncthreads();
    atomicAdd(&bn_sh[(blockIdx.x & 63) * 256 + t], lsum[t]);
    // last-block BN finalize (replaces k_bnfin dispatch)
    __threadfence();
    if (t == 0) {
        int done = atomicAdd(counter, 1);
        isLast = (done == (int)gridDim.x - 1) ? 1 : 0;
    }
    __syncthreads();
    if (isLast) {
        __threadfence();
        if (t < 128) {
            float s = 0.f, s2 = 0.f;
#pragma unroll 8
            for (int k = 0; k < 64; k++) {
                s += bn_sh[k * 256 + t];
                s2 += bn_sh[k * 256 + 128 + t];
            }
            float mean = s * (1.0f / NN);
            float var = s2 * (1.0f / NN) - mean * mean;
            float sc = gamma[t] * rsqrtf(var + BN_EPS);
            aff_out[t] = sc;
            aff_out[128 + t] = beta[t] - mean * sc;
        }
    }
}

// ---- final conv 128->64: 32 nodes/block, N-split x2, fused add-pool (r9) --
__global__ __launch_bounds__(256) void k_final(const ushort* __restrict__ agg,
                                               const ushort* __restrict__ hb,
                                               const ushort* __restrict__ relT,
                                               const ushort* __restrict__ rootT,
                                               const float* __restrict__ bias,
                                               const float* __restrict__ aff,
                                               const int* __restrict__ batch,
                                               float* __restrict__ out) {
    __shared__ __align__(16) float tpf[32 * 68];
    __shared__ float lsc[128], lsh[128];
    __shared__ int bt[32];
    int t = threadIdx.x;
    if (t < 128) { lsc[t] = aff[t]; lsh[t] = aff[128 + t]; }
    if (t < 32) {
        int n = blockIdx.x * 32 + t;
        bt[t] = (n < NN) ? batch[n] : -1;
    }
    int lane = t & 63, wv = t >> 6;
    int ng = wv & 1, nh = wv >> 1;
    int l15 = lane & 15, q = lane >> 4;
    int node0 = blockIdx.x * 32 + ng * 16;
    int nA = min(node0 + l15, NN - 1);
    bfrag a1v[4], a2rv[4];
#pragma unroll
    for (int ks = 0; ks < 4; ks++) {
        a1v[ks] = *(const bfrag*)(agg + (size_t)nA * HID + ks * 32 + q * 8);
        a2rv[ks] = *(const bfrag*)(hb + (size_t)nA * HID + ks * 32 + q * 8);
    }
    __syncthreads();
    f4 acc[2];
    acc[0] = (f4)0.0f; acc[1] = (f4)0.0f;
#pragma unroll
    for (int ks = 0; ks < 4; ks++) {
        float asc[8], ash[8];
        *(f4*)&asc[0] = *(const f4*)&lsc[ks * 32 + q * 8];
        *(f4*)&asc[4] = *(const f4*)&lsc[ks * 32 + q * 8 + 4];
        *(f4*)&ash[0] = *(const f4*)&lsh[ks * 32 + q * 8];
        *(f4*)&ash[4] = *(const f4*)&lsh[ks * 32 + q * 8 + 4];
        bfrag a2;
#pragma unroll
        for (int j = 0; j < 8; j++) {
            float tt = b2f((ushort)a2rv[ks][j]) * asc[j] + ash[j];
            a2[j] = (short)f2b(fmaxf(tt, 0.0f));
        }
#pragma unroll
        for (int nt = 0; nt < 2; nt++) {
            int ntg = nh * 2 + nt;
            bfrag b1 = *(const bfrag*)(relT + (ntg * 16 + l15) * HID + ks * 32 + q * 8);
            acc[nt] = __builtin_amdgcn_mfma_f32_16x16x32_bf16(a1v[ks], b1, acc[nt], 0, 0, 0);
            bfrag b2 = *(const bfrag*)(rootT + (ntg * 16 + l15) * HID + ks * 32 + q * 8);
            acc[nt] = __builtin_amdgcn_mfma_f32_16x16x32_bf16(a2, b2, acc[nt], 0, 0, 0);
        }
    }
#pragma unroll
    for (int nt = 0; nt < 2; nt++) {
        int c = nh * 32 + nt * 16 + l15;
        float bs = bias[c];
#pragma unroll
        for (int r = 0; r < 4; r++)
            tpf[(ng * 16 + q * 4 + r) * 68 + c] = acc[nt][r] + bs;
    }
    __syncthreads();
    // fused global_add_pool: 4 groups x 8 nodes, run-segmented
    int c = t & 63, grp = t >> 6;
    int g = bt[grp * 8];
    if (g >= 0) {
        float pacc = 0.f;
#pragma unroll
        for (int r = 0; r < 8; r++) {
            int b = bt[grp * 8 + r];
            if (b < 0) break;
            float v = tpf[(grp * 8 + r) * 68 + c];
            if (b != g) { atomicAdd(&out[g * OUTC + c], pacc); pacc = 0.f; g = b; }
            pacc += v;
        }
        atomicAdd(&out[g * OUTC + c], pacc);
    }
}

extern "C" void kernel_launch(void* const* d_in, const int* in_sizes, int n_in,
                              void* d_out, int out_size, void* d_ws, size_t ws_size,
                              hipStream_t stream) {
    const float* x      = (const float*)d_in[0];
    const int*   ei     = (const int*)d_in[1];
    const int*   batch  = (const int*)d_in[2];
    const float* lin_w  = (const float*)d_in[3];
    const float* lin_b  = (const float*)d_in[4];
    const float* rel_w  = (const float*)d_in[5];
    const float* root_w = (const float*)d_in[6];
    const float* conv_b = (const float*)d_in[7];
    const float* bn_g   = (const float*)d_in[8];
    const float* bn_b   = (const float*)d_in[9];
    const float* rel_l  = (const float*)d_in[10];
    const float* root_l = (const float*)d_in[11];
    const float* b_l    = (const float*)d_in[12];
    float* out = (float*)d_out;

    char* w = (char*)d_ws;
    ushort* h    = (ushort*)w;   w += (size_t)NN * HID * 2;   // 12.8 MB bf16
    ushort* h2   = (ushort*)w;   w += (size_t)NN * HID * 2;   // 12.8 MB bf16
    ushort* agg  = (ushort*)w;   w += (size_t)NN * HID * 2;   // 12.8 MB bf16
    unsigned* epk= (unsigned*)w; w += (size_t)NE * 4;         // 3.2 MB
    ushort* csr  = (ushort*)w;   w += (size_t)NE * 2;         // 1.6 MB
    int* p_hist  = (int*)w;      w += NPB * NBKT * 4;
    int* bstart  = (int*)w;      w += 800;
    int* btot    = (int*)w;      w += 800;
    int* offs    = (int*)w;      w += 200064;
    float* aff   = (float*)w;    w += 4 * 256 * 4;            // per-layer (sc,sh)
    float* bn_sh = (float*)w;    w += NLAY * 64 * 256 * 4;    // 192 KB shards
    int* cnt     = (int*)w;      w += 64;
    ushort* wT   = (ushort*)w;   w += 131072 * 2;

    k_prep<<<512, 256, 0, stream>>>(lin_w, rel_w, root_w, rel_l, root_l, wT,
                                    aff, bn_sh, out, cnt);
    k_part1<<<NPB, 256, 0, stream>>>(ei, p_hist);
    k_part2a<<<NBKT, 256, 0, stream>>>(p_hist, btot);
    k_part2b<<<1, 256, 0, stream>>>(btot, bstart, offs);
    k_part3<<<NPB, 256, 0, stream>>>(ei, p_hist, bstart, epk);
    k_csr<<<NBKT, 256, 0, stream>>>(epk, bstart, csr, offs);

    k_lin<<<(NN + 63) / 64, 256, 0, stream>>>(x, wT, lin_b, h);

    int conv_blocks = (NN + 31) / 32;  // 1563
    ushort* hb = h;
    ushort* ho = h2;
    for (int i = 0; i < NLAY; i++) {
        float negk = (i == 0) ? 1.0f : 0.0f;
        k_agg<<<(NN + 3) / 4, 256, 0, stream>>>(hb, offs, csr, aff + i * 256, negk, agg);
        k_conv<<<conv_blocks, 256, 0, stream>>>(agg, hb,
                                                wT + 16384 + i * 16384,
                                                wT + 65536 + i * 16384,
                                                conv_b + i * HID,
                                                aff + i * 256, negk,
                                                bn_sh + i * 64 * 256, ho,
                                                bn_g + i * HID, bn_b + i * HID,
                                                aff + (i + 1) * 256, cnt + i);
        ushort* tmp = hb; hb = ho; ho = tmp;
    }

    k_agg<<<(NN + 3) / 4, 256, 0, stream>>>(hb, offs, csr, aff + 3 * 256, 0.0f, agg);
    k_final<<<conv_blocks, 256, 0, stream>>>(agg, hb, wT + 114688, wT + 122880, b_l,
                                             aff + 3 * 256, batch, out);
}

// Round 14
// 402.370 us; speedup vs baseline: 2.0230x; 2.0230x over previous
//
#include <hip/hip_runtime.h>

#define NN 50000
#define NE 800000
#define HID 128
#define OUTC 64
#define NG 128
#define NLAY 3
#define BN_EPS 1e-5f
#define NBKT 196          // ceil(NN/256) buckets of 256 nodes
#define NPB 256           // partition blocks
#define EPB ((NE + NPB - 1) / NPB)
#define LCAP 8192

typedef __attribute__((ext_vector_type(8))) short bfrag;
typedef __attribute__((ext_vector_type(4))) float f4;

__device__ __forceinline__ ushort f2b(float f) {
    union { float f; unsigned u; } x; x.f = f;
    unsigned u = x.u;
    unsigned r = (u + 0x7fffu + ((u >> 16) & 1u)) >> 16;  // RNE
    return (ushort)r;
}
__device__ __forceinline__ float b2f(ushort b) {
    union { unsigned u; float f; } x; x.u = ((unsigned)b) << 16; return x.f;
}

// ---- weight prep + buffer init -------------------------------------------
__global__ void k_prep(const float* __restrict__ lin_w, const float* __restrict__ rel_w,
                       const float* __restrict__ root_w, const float* __restrict__ rel_l,
                       const float* __restrict__ root_l, ushort* __restrict__ wT,
                       float* __restrict__ aff, float* __restrict__ bn_sh,
                       float* __restrict__ out) {
    int idx = blockIdx.x * 256 + threadIdx.x;
    if (idx < 7 * 16384) {
        int m = idx >> 14, r = idx & 16383;
        int n = r >> 7, k = r & 127;
        const float* src = (m == 0) ? lin_w
                         : (m <= 3 ? rel_w + (m - 1) * 16384 : root_w + (m - 4) * 16384);
        wT[idx] = f2b(src[k * 128 + n]);
    } else {
        int r = idx - 7 * 16384;
        int m = r >> 13, rr = r & 8191;
        int n = rr >> 7, k = rr & 127;
        const float* src = m ? root_l : rel_l;
        wT[idx] = f2b(src[k * 64 + n]);
    }
    if (idx < 128) aff[idx] = 1.0f;                 // layer-0 identity scale
    else if (idx < 256) aff[idx] = 0.0f;            // layer-0 zero shift
    if (idx < NG * OUTC) out[idx] = 0.0f;
    if (idx < NLAY * 64 * 256) bn_sh[idx] = 0.0f;
}

// ---- CSR build via bucketed counting sort (LDS atomics only) --------------
__global__ __launch_bounds__(256) void k_part1(const int* __restrict__ ei,
                                               int* __restrict__ p_hist) {
    __shared__ int hist[NBKT];
    int t = threadIdx.x;
    if (t < NBKT) hist[t] = 0;
    __syncthreads();
    int e0 = blockIdx.x * EPB, e1 = min(e0 + EPB, NE);
    for (int e = e0 + t; e < e1; e += 256)
        atomicAdd(&hist[ei[NE + e] >> 8], 1);
    __syncthreads();
    if (t < NBKT) p_hist[blockIdx.x * NBKT + t] = hist[t];
}

__global__ void k_part2a(int* __restrict__ p_hist, int* __restrict__ btot) {
    __shared__ int s[256];
    int k = blockIdx.x, t = threadIdx.x;
    int v = p_hist[t * NBKT + k];
    s[t] = v;
    __syncthreads();
    for (int d = 1; d < 256; d <<= 1) {
        int u = 0;
        if (t >= d) u = s[t - d];
        __syncthreads();
        s[t] += u;
        __syncthreads();
    }
    p_hist[t * NBKT + k] = s[t] - v;   // exclusive over blocks
    if (t == 255) btot[k] = s[255];
}

__global__ void k_part2b(const int* __restrict__ btot, int* __restrict__ bstart,
                         int* __restrict__ offs) {
    __shared__ int s[256];
    int t = threadIdx.x;
    int v = (t < NBKT) ? btot[t] : 0;
    s[t] = v;
    __syncthreads();
    for (int d = 1; d < 256; d <<= 1) {
        int u = 0;
        if (t >= d) u = s[t - d];
        __syncthreads();
        s[t] += u;
        __syncthreads();
    }
    if (t < NBKT) bstart[t] = s[t] - v;
    if (t == 0) { bstart[NBKT] = NE; offs[NN] = NE; }
}

__global__ __launch_bounds__(256) void k_part3(const int* __restrict__ ei,
                                               const int* __restrict__ p_hist,
                                               const int* __restrict__ bstart,
                                               unsigned* __restrict__ epk) {
    __shared__ int cur[NBKT];
    int t = threadIdx.x;
    if (t < NBKT) cur[t] = p_hist[blockIdx.x * NBKT + t] + bstart[t];
    __syncthreads();
    int e0 = blockIdx.x * EPB, e1 = min(e0 + EPB, NE);
    for (int e = e0 + t; e < e1; e += 256) {
        int d = ei[NE + e], s = ei[e];
        int p = atomicAdd(&cur[d >> 8], 1);
        epk[p] = (unsigned)s | ((unsigned)(d & 255) << 16);
    }
}

__global__ __launch_bounds__(256) void k_csr(const unsigned* __restrict__ epk,
                                             const int* __restrict__ bstart,
                                             ushort* __restrict__ csr,
                                             int* __restrict__ offs) {
    __shared__ int cnt[256];
    __shared__ int cur[256];
    __shared__ ushort lcsr[LCAP];
    int b = blockIdx.x, t = threadIdx.x;
    int e0 = bstart[b], e1 = bstart[b + 1];
    int sz = e1 - e0;
    cnt[t] = 0;
    __syncthreads();
    for (int i = t; i < sz; i += 256)
        atomicAdd(&cnt[epk[e0 + i] >> 16], 1);
    __syncthreads();
    int v = cnt[t];
    for (int d = 1; d < 256; d <<= 1) {
        int u = 0;
        if (t >= d) u = cnt[t - d];
        __syncthreads();
        cnt[t] += u;
        __syncthreads();
    }
    int excl = cnt[t] - v;
    cur[t] = excl;
    int node = b * 256 + t;
    if (node < NN) offs[node] = e0 + excl;
    __syncthreads();
    for (int i = t; i < sz; i += 256) {
        unsigned pk = epk[e0 + i];
        int p = atomicAdd(&cur[pk >> 16], 1);
        lcsr[p] = (ushort)(pk & 0xffffu);
    }
    __syncthreads();
    for (int i = t; i < sz; i += 256) csr[e0 + i] = lcsr[i];
}

// ---- initial linear: h = bf16(x @ lin_w + lin_b) --------------------------
__global__ __launch_bounds__(256) void k_lin(const float* __restrict__ x,
                                             const ushort* __restrict__ wT,
                                             const float* __restrict__ bias,
                                             ushort* __restrict__ h) {
    __shared__ __align__(16) ushort tp[4][16 * 136];
    int t = threadIdx.x;
    int lane = t & 63, wv = t >> 6;
    int node0 = (blockIdx.x * 4 + wv) * 16;
    int l15 = lane & 15, q = lane >> 4;
    int nA = min(node0 + l15, NN - 1);
    f4 acc[8];
#pragma unroll
    for (int nt = 0; nt < 8; nt++) acc[nt] = (f4)0.0f;
#pragma unroll
    for (int ks = 0; ks < 4; ks++) {
        const float* ap = x + (size_t)nA * HID + ks * 32 + q * 8;
        f4 x0 = *(const f4*)ap;
        f4 x1 = *(const f4*)(ap + 4);
        bfrag a;
#pragma unroll
        for (int j = 0; j < 4; j++) { a[j] = (short)f2b(x0[j]); a[4 + j] = (short)f2b(x1[j]); }
#pragma unroll
        for (int nt = 0; nt < 8; nt++) {
            bfrag b = *(const bfrag*)(wT + (nt * 16 + l15) * HID + ks * 32 + q * 8);
            acc[nt] = __builtin_amdgcn_mfma_f32_16x16x32_bf16(a, b, acc[nt], 0, 0, 0);
        }
    }
#pragma unroll
    for (int nt = 0; nt < 8; nt++) {
        float bs = bias[nt * 16 + l15];
#pragma unroll
        for (int r = 0; r < 4; r++)
            tp[wv][(q * 4 + r) * 136 + nt * 16 + l15] = f2b(acc[nt][r] + bs);
    }
    __syncthreads();
#pragma unroll
    for (int i = 0; i < 4; i++) {
        int nr = node0 + i * 4 + q;
        if (nr < NN) {
            bfrag tv = *(const bfrag*)&tp[wv][(i * 4 + q) * 136 + l15 * 8];
            *(bfrag*)(h + (size_t)nr * HID + l15 * 8) = tv;
        }
    }
}

// ---- aggregation with fused BN+relu (r5/r7/r9 proven form) ----------------
__global__ __launch_bounds__(256) void k_agg(const ushort* __restrict__ hb,
                                             const int* __restrict__ offs,
                                             const ushort* __restrict__ csr,
                                             const float* __restrict__ aff,
                                             float negk,
                                             ushort* __restrict__ agg) {
    int gw = (blockIdx.x * 256 + threadIdx.x) >> 6;  // one wave per node
    int lane = threadIdx.x & 63;
    int slot = lane >> 4, c16 = lane & 15;
    if (gw >= NN) return;
    float scv[8], shv[8];
    *(f4*)&scv[0] = *(const f4*)(aff + c16 * 8);
    *(f4*)&scv[4] = *(const f4*)(aff + c16 * 8 + 4);
    *(f4*)&shv[0] = *(const f4*)(aff + 128 + c16 * 8);
    *(f4*)&shv[4] = *(const f4*)(aff + 128 + c16 * 8 + 4);
    int e0 = offs[gw], e1 = offs[gw + 1];
    float a[8];
#pragma unroll
    for (int j = 0; j < 8; j++) a[j] = 0.f;
    int base = e0;
    for (; base + 8 <= e1; base += 8) {
        int s0 = csr[base + slot];
        int s1 = csr[base + 4 + slot];
        bfrag v0 = *(const bfrag*)(hb + (size_t)s0 * HID + c16 * 8);
        bfrag v1 = *(const bfrag*)(hb + (size_t)s1 * HID + c16 * 8);
#pragma unroll
        for (int j = 0; j < 8; j++) {
            float t0 = b2f((ushort)v0[j]) * scv[j] + shv[j];
            float t1 = b2f((ushort)v1[j]) * scv[j] + shv[j];
            a[j] += fmaxf(t0, t0 * negk) + fmaxf(t1, t1 * negk);
        }
    }
    if (base + 4 <= e1) {
        int s0 = csr[base + slot];
        bfrag v0 = *(const bfrag*)(hb + (size_t)s0 * HID + c16 * 8);
#pragma unroll
        for (int j = 0; j < 8; j++) {
            float t0 = b2f((ushort)v0[j]) * scv[j] + shv[j];
            a[j] += fmaxf(t0, t0 * negk);
        }
        base += 4;
    }
    int rem = e1 - base;
    if (slot < rem) {
        int s0 = csr[base + slot];
        bfrag v0 = *(const bfrag*)(hb + (size_t)s0 * HID + c16 * 8);
#pragma unroll
        for (int j = 0; j < 8; j++) {
            float t0 = b2f((ushort)v0[j]) * scv[j] + shv[j];
            a[j] += fmaxf(t0, t0 * negk);
        }
    }
#pragma unroll
    for (int j = 0; j < 8; j++) {
        a[j] += __shfl_xor(a[j], 16);
        a[j] += __shfl_xor(a[j], 32);
    }
    if (slot == 0) {
        bfrag o;
#pragma unroll
        for (int j = 0; j < 8; j++) o[j] = (short)f2b(a[j]);
        *(bfrag*)(agg + (size_t)gw * HID + c16 * 8) = o;
    }
}

// ---- conv layer: 32 nodes/block, N-split x2 (r7/r9 proven form) -----------
__global__ __launch_bounds__(256) void k_conv(const ushort* __restrict__ agg,
                                              const ushort* __restrict__ hb,
                                              const ushort* __restrict__ relT,
                                              const ushort* __restrict__ rootT,
                                              const float* __restrict__ bias,
                                              const float* __restrict__ aff,
                                              float negk,
                                              float* __restrict__ bn_sh,
                                              ushort* __restrict__ h2) {
    __shared__ __align__(16) ushort tp[32 * 136];     // conv result (pre-residual)
    __shared__ __align__(16) ushort rtile[32 * 136];  // BN'd root rows
    __shared__ float lsum[256];
    __shared__ float lsc[128], lsh[128];
    int t = threadIdx.x;
    lsum[t] = 0.f;
    if (t < 128) { lsc[t] = aff[t]; lsh[t] = aff[128 + t]; }
    int lane = t & 63, wv = t >> 6;
    int ng = wv & 1, nh = wv >> 1;    // node-group, channel-half
    int l15 = lane & 15, q = lane >> 4;
    int node0 = blockIdx.x * 32 + ng * 16;
    int nA = min(node0 + l15, NN - 1);
    bfrag a1v[4], a2rv[4];
#pragma unroll
    for (int ks = 0; ks < 4; ks++) {
        a1v[ks] = *(const bfrag*)(agg + (size_t)nA * HID + ks * 32 + q * 8);
        a2rv[ks] = *(const bfrag*)(hb + (size_t)nA * HID + ks * 32 + q * 8);
    }
    __syncthreads();  // lsc/lsh + lsum init visible
    bfrag a2[4];
#pragma unroll
    for (int ks = 0; ks < 4; ks++) {
        float asc[8], ash[8];
        *(f4*)&asc[0] = *(const f4*)&lsc[ks * 32 + q * 8];
        *(f4*)&asc[4] = *(const f4*)&lsc[ks * 32 + q * 8 + 4];
        *(f4*)&ash[0] = *(const f4*)&lsh[ks * 32 + q * 8];
        *(f4*)&ash[4] = *(const f4*)&lsh[ks * 32 + q * 8 + 4];
#pragma unroll
        for (int j = 0; j < 8; j++) {
            float tt = b2f((ushort)a2rv[ks][j]) * asc[j] + ash[j];
            a2[ks][j] = (short)f2b(fmaxf(tt, tt * negk));
        }
        if (nh == 0)
            *(bfrag*)&rtile[(ng * 16 + l15) * 136 + ks * 32 + q * 8] = a2[ks];
    }
    f4 acc[4];
#pragma unroll
    for (int nt = 0; nt < 4; nt++) acc[nt] = (f4)0.0f;
#pragma unroll
    for (int ks = 0; ks < 4; ks++) {
#pragma unroll
        for (int nt = 0; nt < 4; nt++) {
            int ntg = nh * 4 + nt;
            bfrag b1 = *(const bfrag*)(relT + (ntg * 16 + l15) * HID + ks * 32 + q * 8);
            acc[nt] = __builtin_amdgcn_mfma_f32_16x16x32_bf16(a1v[ks], b1, acc[nt], 0, 0, 0);
            bfrag b2 = *(const bfrag*)(rootT + (ntg * 16 + l15) * HID + ks * 32 + q * 8);
            acc[nt] = __builtin_amdgcn_mfma_f32_16x16x32_bf16(a2[ks], b2, acc[nt], 0, 0, 0);
        }
    }
#pragma unroll
    for (int nt = 0; nt < 4; nt++) {
        int c = nh * 64 + nt * 16 + l15;
        float bs = bias[c];
#pragma unroll
        for (int r = 0; r < 4; r++)
            tp[(ng * 16 + q * 4 + r) * 136 + c] = f2b(acc[nt][r] + bs);
    }
    __syncthreads();
    // store path: thread = (row, 16-channel chunk)
    {
        int row = t >> 3, cb = (t & 7) * 16;
        int nr = blockIdx.x * 32 + row;
        if (nr < NN) {
            bfrag t0 = *(const bfrag*)&tp[row * 136 + cb];
            bfrag t1 = *(const bfrag*)&tp[row * 136 + cb + 8];
            bfrag r0 = *(const bfrag*)&rtile[row * 136 + cb];
            bfrag r1 = *(const bfrag*)&rtile[row * 136 + cb + 8];
            bfrag o0, o1;
#pragma unroll
            for (int j = 0; j < 8; j++) {
                o0[j] = (short)f2b(b2f((ushort)t0[j]) + b2f((ushort)r0[j]));
                o1[j] = (short)f2b(b2f((ushort)t1[j]) + b2f((ushort)r1[j]));
            }
            *(bfrag*)(h2 + (size_t)nr * HID + cb) = o0;
            *(bfrag*)(h2 + (size_t)nr * HID + cb + 8) = o1;
        }
    }
    // stats pass: wave wv covers rows wv*8..+8; lane covers channel pair (2l,2l+1)
    {
        float s0 = 0.f, s1 = 0.f, q0 = 0.f, q1 = 0.f;
        int c2 = lane * 2;
#pragma unroll
        for (int r = 0; r < 8; r++) {
            int row = wv * 8 + r;
            int nr = blockIdx.x * 32 + row;
            if (nr < NN) {
                unsigned tu = *(const unsigned*)&tp[row * 136 + c2];
                unsigned ru = *(const unsigned*)&rtile[row * 136 + c2];
                float v0 = b2f((ushort)(tu & 0xffffu)) + b2f((ushort)(ru & 0xffffu));
                float v1 = b2f((ushort)(tu >> 16)) + b2f((ushort)(ru >> 16));
                s0 += v0; s1 += v1; q0 += v0 * v0; q1 += v1 * v1;
            }
        }
        atomicAdd(&lsum[c2], s0);
        atomicAdd(&lsum[c2 + 1], s1);
        atomicAdd(&lsum[128 + c2], q0);
        atomicAdd(&lsum[128 + c2 + 1], q1);
    }
    __syncthreads();
    atomicAdd(&bn_sh[(blockIdx.x & 63) * 256 + t], lsum[t]);
}

// ---- reduce shards + compute next-layer affine (sc, sh) -------------------
__global__ void k_bnfin(const float* __restrict__ bn_sh, const float* __restrict__ gamma,
                        const float* __restrict__ beta, float* __restrict__ aff_out) {
    int t = threadIdx.x;  // 128 = channel
    float s = 0.f, s2 = 0.f;
#pragma unroll 8
    for (int k = 0; k < 64; k++) {
        s += bn_sh[k * 256 + t];
        s2 += bn_sh[k * 256 + 128 + t];
    }
    float mean = s * (1.0f / NN);
    float var = s2 * (1.0f / NN) - mean * mean;
    float sc = gamma[t] * rsqrtf(var + BN_EPS);
    aff_out[t] = sc;
    aff_out[128 + t] = beta[t] - mean * sc;
}

// ---- final conv 128->64: 32 nodes/block, N-split x2, fused add-pool -------
__global__ __launch_bounds__(256) void k_final(const ushort* __restrict__ agg,
                                               const ushort* __restrict__ hb,
                                               const ushort* __restrict__ relT,
                                               const ushort* __restrict__ rootT,
                                               const float* __restrict__ bias,
                                               const float* __restrict__ aff,
                                               const int* __restrict__ batch,
                                               float* __restrict__ out) {
    __shared__ __align__(16) float tpf[32 * 68];
    __shared__ float lsc[128], lsh[128];
    __shared__ int bt[32];
    int t = threadIdx.x;
    if (t < 128) { lsc[t] = aff[t]; lsh[t] = aff[128 + t]; }
    if (t < 32) {
        int n = blockIdx.x * 32 + t;
        bt[t] = (n < NN) ? batch[n] : -1;
    }
    int lane = t & 63, wv = t >> 6;
    int ng = wv & 1, nh = wv >> 1;
    int l15 = lane & 15, q = lane >> 4;
    int node0 = blockIdx.x * 32 + ng * 16;
    int nA = min(node0 + l15, NN - 1);
    bfrag a1v[4], a2rv[4];
#pragma unroll
    for (int ks = 0; ks < 4; ks++) {
        a1v[ks] = *(const bfrag*)(agg + (size_t)nA * HID + ks * 32 + q * 8);
        a2rv[ks] = *(const bfrag*)(hb + (size_t)nA * HID + ks * 32 + q * 8);
    }
    __syncthreads();
    f4 acc[2];
    acc[0] = (f4)0.0f; acc[1] = (f4)0.0f;
#pragma unroll
    for (int ks = 0; ks < 4; ks++) {
        float asc[8], ash[8];
        *(f4*)&asc[0] = *(const f4*)&lsc[ks * 32 + q * 8];
        *(f4*)&asc[4] = *(const f4*)&lsc[ks * 32 + q * 8 + 4];
        *(f4*)&ash[0] = *(const f4*)&lsh[ks * 32 + q * 8];
        *(f4*)&ash[4] = *(const f4*)&lsh[ks * 32 + q * 8 + 4];
        bfrag a2;
#pragma unroll
        for (int j = 0; j < 8; j++) {
            float tt = b2f((ushort)a2rv[ks][j]) * asc[j] + ash[j];
            a2[j] = (short)f2b(fmaxf(tt, 0.0f));
        }
#pragma unroll
        for (int nt = 0; nt < 2; nt++) {
            int ntg = nh * 2 + nt;
            bfrag b1 = *(const bfrag*)(relT + (ntg * 16 + l15) * HID + ks * 32 + q * 8);
            acc[nt] = __builtin_amdgcn_mfma_f32_16x16x32_bf16(a1v[ks], b1, acc[nt], 0, 0, 0);
            bfrag b2 = *(const bfrag*)(rootT + (ntg * 16 + l15) * HID + ks * 32 + q * 8);
            acc[nt] = __builtin_amdgcn_mfma_f32_16x16x32_bf16(a2, b2, acc[nt], 0, 0, 0);
        }
    }
#pragma unroll
    for (int nt = 0; nt < 2; nt++) {
        int c = nh * 32 + nt * 16 + l15;
        float bs = bias[c];
#pragma unroll
        for (int r = 0; r < 4; r++)
            tpf[(ng * 16 + q * 4 + r) * 68 + c] = acc[nt][r] + bs;
    }
    __syncthreads();
    // fused global_add_pool: 4 groups x 8 nodes, run-segmented
    int c = t & 63, grp = t >> 6;
    int g = bt[grp * 8];
    if (g >= 0) {
        float pacc = 0.f;
#pragma unroll
        for (int r = 0; r < 8; r++) {
            int b = bt[grp * 8 + r];
            if (b < 0) break;
            float v = tpf[(grp * 8 + r) * 68 + c];
            if (b != g) { atomicAdd(&out[g * OUTC + c], pacc); pacc = 0.f; g = b; }
            pacc += v;
        }
        atomicAdd(&out[g * OUTC + c], pacc);
    }
}

extern "C" void kernel_launch(void* const* d_in, const int* in_sizes, int n_in,
                              void* d_out, int out_size, void* d_ws, size_t ws_size,
                              hipStream_t stream) {
    const float* x      = (const float*)d_in[0];
    const int*   ei     = (const int*)d_in[1];
    const int*   batch  = (const int*)d_in[2];
    const float* lin_w  = (const float*)d_in[3];
    const float* lin_b  = (const float*)d_in[4];
    const float* rel_w  = (const float*)d_in[5];
    const float* root_w = (const float*)d_in[6];
    const float* conv_b = (const float*)d_in[7];
    const float* bn_g   = (const float*)d_in[8];
    const float* bn_b   = (const float*)d_in[9];
    const float* rel_l  = (const float*)d_in[10];
    const float* root_l = (const float*)d_in[11];
    const float* b_l    = (const float*)d_in[12];
    float* out = (float*)d_out;

    char* w = (char*)d_ws;
    ushort* h    = (ushort*)w;   w += (size_t)NN * HID * 2;   // 12.8 MB bf16
    ushort* h2   = (ushort*)w;   w += (size_t)NN * HID * 2;   // 12.8 MB bf16
    ushort* agg  = (ushort*)w;   w += (size_t)NN * HID * 2;   // 12.8 MB bf16
    unsigned* epk= (unsigned*)w; w += (size_t)NE * 4;         // 3.2 MB
    ushort* csr  = (ushort*)w;   w += (size_t)NE * 2;         // 1.6 MB
    int* p_hist  = (int*)w;      w += NPB * NBKT * 4;
    int* bstart  = (int*)w;      w += 800;
    int* btot    = (int*)w;      w += 800;
    int* offs    = (int*)w;      w += 200064;
    float* aff   = (float*)w;    w += 4 * 256 * 4;            // per-layer (sc,sh)
    float* bn_sh = (float*)w;    w += NLAY * 64 * 256 * 4;    // 192 KB shards
    ushort* wT   = (ushort*)w;   w += 131072 * 2;

    k_prep<<<512, 256, 0, stream>>>(lin_w, rel_w, root_w, rel_l, root_l, wT,
                                    aff, bn_sh, out);
    k_part1<<<NPB, 256, 0, stream>>>(ei, p_hist);
    k_part2a<<<NBKT, 256, 0, stream>>>(p_hist, btot);
    k_part2b<<<1, 256, 0, stream>>>(btot, bstart, offs);
    k_part3<<<NPB, 256, 0, stream>>>(ei, p_hist, bstart, epk);
    k_csr<<<NBKT, 256, 0, stream>>>(epk, bstart, csr, offs);

    k_lin<<<(NN + 63) / 64, 256, 0, stream>>>(x, wT, lin_b, h);

    int conv_blocks = (NN + 31) / 32;  // 1563
    ushort* hb = h;
    ushort* ho = h2;
    for (int i = 0; i < NLAY; i++) {
        float negk = (i == 0) ? 1.0f : 0.0f;
        k_agg<<<(NN + 3) / 4, 256, 0, stream>>>(hb, offs, csr, aff + i * 256, negk, agg);
        k_conv<<<conv_blocks, 256, 0, stream>>>(agg, hb,
                                                wT + 16384 + i * 16384,
                                                wT + 65536 + i * 16384,
                                                conv_b + i * HID,
                                                aff + i * 256, negk,
                                                bn_sh + i * 64 * 256, ho);
        k_bnfin<<<1, 128, 0, stream>>>(bn_sh + i * 64 * 256, bn_g + i * HID,
                                       bn_b + i * HID, aff + (i + 1) * 256);
        ushort* tmp = hb; hb = ho; ho = tmp;
    }

    k_agg<<<(NN + 3) / 4, 256, 0, stream>>>(hb, offs, csr, aff + 3 * 256, 0.0f, agg);
    k_final<<<conv_blocks, 256, 0, stream>>>(agg, hb, wT + 114688, wT + 122880, b_l,
                                             aff + 3 * 256, batch, out);
}

// Round 15
// 400.058 us; speedup vs baseline: 2.0347x; 1.0058x over previous
//
#include <hip/hip_runtime.h>

#define NN 50000
#define NE 800000
#define HID 128
#define OUTC 64
#define NG 128
#define NLAY 3
#define BN_EPS 1e-5f
#define NBKT 196          // ceil(NN/256) buckets of 256 nodes
#define NPB 256           // partition blocks
#define EPB ((NE + NPB - 1) / NPB)
#define LCAP 8192
#define LIN_BLOCKS 782    // ceil(NN/64)

typedef __attribute__((ext_vector_type(8))) short bfrag;
typedef __attribute__((ext_vector_type(4))) float f4;

__device__ __forceinline__ ushort f2b(float f) {
    union { float f; unsigned u; } x; x.f = f;
    unsigned u = x.u;
    unsigned r = (u + 0x7fffu + ((u >> 16) & 1u)) >> 16;  // RNE
    return (ushort)r;
}
__device__ __forceinline__ float b2f(ushort b) {
    union { unsigned u; float f; } x; x.u = ((unsigned)b) << 16; return x.f;
}

// ---- merged: weight prep + buffer init (blocks 0-511) | part1 (512-767) ---
__global__ __launch_bounds__(256) void k_init(const float* __restrict__ lin_w,
                                              const float* __restrict__ rel_w,
                                              const float* __restrict__ root_w,
                                              const float* __restrict__ rel_l,
                                              const float* __restrict__ root_l,
                                              ushort* __restrict__ wT,
                                              float* __restrict__ aff,
                                              float* __restrict__ bn_sh,
                                              float* __restrict__ out,
                                              const int* __restrict__ ei,
                                              int* __restrict__ p_hist) {
    if (blockIdx.x < 512) {
        int idx = blockIdx.x * 256 + threadIdx.x;
        if (idx < 7 * 16384) {
            int m = idx >> 14, r = idx & 16383;
            int n = r >> 7, k = r & 127;
            const float* src = (m == 0) ? lin_w
                             : (m <= 3 ? rel_w + (m - 1) * 16384 : root_w + (m - 4) * 16384);
            wT[idx] = f2b(src[k * 128 + n]);
        } else {
            int r = idx - 7 * 16384;
            int m = r >> 13, rr = r & 8191;
            int n = rr >> 7, k = rr & 127;
            const float* src = m ? root_l : rel_l;
            wT[idx] = f2b(src[k * 64 + n]);
        }
        if (idx < 128) aff[idx] = 1.0f;                 // layer-0 identity scale
        else if (idx < 256) aff[idx] = 0.0f;            // layer-0 zero shift
        if (idx < NG * OUTC) out[idx] = 0.0f;
        if (idx < NLAY * 64 * 256) bn_sh[idx] = 0.0f;
    } else {
        __shared__ int hist[NBKT];
        int pb = blockIdx.x - 512;
        int t = threadIdx.x;
        if (t < NBKT) hist[t] = 0;
        __syncthreads();
        int e0 = pb * EPB, e1 = min(e0 + EPB, NE);
        for (int e = e0 + t; e < e1; e += 256)
            atomicAdd(&hist[ei[NE + e] >> 8], 1);
        __syncthreads();
        if (t < NBKT) p_hist[pb * NBKT + t] = hist[t];
    }
}

// ---- merged: k_lin (blocks 0-781) | part2a (782-977) ----------------------
__global__ __launch_bounds__(256) void k_linscan(const float* __restrict__ x,
                                                 const ushort* __restrict__ wT,
                                                 const float* __restrict__ bias,
                                                 ushort* __restrict__ h,
                                                 int* __restrict__ p_hist,
                                                 int* __restrict__ btot) {
    if (blockIdx.x < LIN_BLOCKS) {
        __shared__ __align__(16) ushort tp[4][16 * 136];
        int t = threadIdx.x;
        int lane = t & 63, wv = t >> 6;
        int node0 = (blockIdx.x * 4 + wv) * 16;
        int l15 = lane & 15, q = lane >> 4;
        int nA = min(node0 + l15, NN - 1);
        f4 acc[8];
#pragma unroll
        for (int nt = 0; nt < 8; nt++) acc[nt] = (f4)0.0f;
#pragma unroll
        for (int ks = 0; ks < 4; ks++) {
            const float* ap = x + (size_t)nA * HID + ks * 32 + q * 8;
            f4 x0 = *(const f4*)ap;
            f4 x1 = *(const f4*)(ap + 4);
            bfrag a;
#pragma unroll
            for (int j = 0; j < 4; j++) { a[j] = (short)f2b(x0[j]); a[4 + j] = (short)f2b(x1[j]); }
#pragma unroll
            for (int nt = 0; nt < 8; nt++) {
                bfrag b = *(const bfrag*)(wT + (nt * 16 + l15) * HID + ks * 32 + q * 8);
                acc[nt] = __builtin_amdgcn_mfma_f32_16x16x32_bf16(a, b, acc[nt], 0, 0, 0);
            }
        }
#pragma unroll
        for (int nt = 0; nt < 8; nt++) {
            float bs = bias[nt * 16 + l15];
#pragma unroll
            for (int r = 0; r < 4; r++)
                tp[wv][(q * 4 + r) * 136 + nt * 16 + l15] = f2b(acc[nt][r] + bs);
        }
        __syncthreads();
#pragma unroll
        for (int i = 0; i < 4; i++) {
            int nr = node0 + i * 4 + q;
            if (nr < NN) {
                bfrag tv = *(const bfrag*)&tp[wv][(i * 4 + q) * 136 + l15 * 8];
                *(bfrag*)(h + (size_t)nr * HID + l15 * 8) = tv;
            }
        }
    } else {
        __shared__ int s[256];
        int k = blockIdx.x - LIN_BLOCKS, t = threadIdx.x;
        int v = p_hist[t * NBKT + k];
        s[t] = v;
        __syncthreads();
        for (int d = 1; d < 256; d <<= 1) {
            int u = 0;
            if (t >= d) u = s[t - d];
            __syncthreads();
            s[t] += u;
            __syncthreads();
        }
        p_hist[t * NBKT + k] = s[t] - v;   // exclusive over blocks
        if (t == 255) btot[k] = s[255];
    }
}

__global__ void k_part2b(const int* __restrict__ btot, int* __restrict__ bstart,
                         int* __restrict__ offs) {
    __shared__ int s[256];
    int t = threadIdx.x;
    int v = (t < NBKT) ? btot[t] : 0;
    s[t] = v;
    __syncthreads();
    for (int d = 1; d < 256; d <<= 1) {
        int u = 0;
        if (t >= d) u = s[t - d];
        __syncthreads();
        s[t] += u;
        __syncthreads();
    }
    if (t < NBKT) bstart[t] = s[t] - v;
    if (t == 0) { bstart[NBKT] = NE; offs[NN] = NE; }
}

__global__ __launch_bounds__(256) void k_part3(const int* __restrict__ ei,
                                               const int* __restrict__ p_hist,
                                               const int* __restrict__ bstart,
                                               unsigned* __restrict__ epk) {
    __shared__ int cur[NBKT];
    int t = threadIdx.x;
    if (t < NBKT) cur[t] = p_hist[blockIdx.x * NBKT + t] + bstart[t];
    __syncthreads();
    int e0 = blockIdx.x * EPB, e1 = min(e0 + EPB, NE);
    for (int e = e0 + t; e < e1; e += 256) {
        int d = ei[NE + e], s = ei[e];
        int p = atomicAdd(&cur[d >> 8], 1);
        epk[p] = (unsigned)s | ((unsigned)(d & 255) << 16);
    }
}

__global__ __launch_bounds__(256) void k_csr(const unsigned* __restrict__ epk,
                                             const int* __restrict__ bstart,
                                             ushort* __restrict__ csr,
                                             int* __restrict__ offs) {
    __shared__ int cnt[256];
    __shared__ int cur[256];
    __shared__ ushort lcsr[LCAP];
    int b = blockIdx.x, t = threadIdx.x;
    int e0 = bstart[b], e1 = bstart[b + 1];
    int sz = e1 - e0;
    cnt[t] = 0;
    __syncthreads();
    for (int i = t; i < sz; i += 256)
        atomicAdd(&cnt[epk[e0 + i] >> 16], 1);
    __syncthreads();
    int v = cnt[t];
    for (int d = 1; d < 256; d <<= 1) {
        int u = 0;
        if (t >= d) u = cnt[t - d];
        __syncthreads();
        cnt[t] += u;
        __syncthreads();
    }
    int excl = cnt[t] - v;
    cur[t] = excl;
    int node = b * 256 + t;
    if (node < NN) offs[node] = e0 + excl;
    __syncthreads();
    for (int i = t; i < sz; i += 256) {
        unsigned pk = epk[e0 + i];
        int p = atomicAdd(&cur[pk >> 16], 1);
        lcsr[p] = (ushort)(pk & 0xffffu);
    }
    __syncthreads();
    for (int i = t; i < sz; i += 256) csr[e0 + i] = lcsr[i];
}

// ---- aggregation with fused BN+relu (r5/r7/r9 proven form) ----------------
__global__ __launch_bounds__(256) void k_agg(const ushort* __restrict__ hb,
                                             const int* __restrict__ offs,
                                             const ushort* __restrict__ csr,
                                             const float* __restrict__ aff,
                                             float negk,
                                             ushort* __restrict__ agg) {
    int gw = (blockIdx.x * 256 + threadIdx.x) >> 6;  // one wave per node
    int lane = threadIdx.x & 63;
    int slot = lane >> 4, c16 = lane & 15;
    if (gw >= NN) return;
    float scv[8], shv[8];
    *(f4*)&scv[0] = *(const f4*)(aff + c16 * 8);
    *(f4*)&scv[4] = *(const f4*)(aff + c16 * 8 + 4);
    *(f4*)&shv[0] = *(const f4*)(aff + 128 + c16 * 8);
    *(f4*)&shv[4] = *(const f4*)(aff + 128 + c16 * 8 + 4);
    int e0 = offs[gw], e1 = offs[gw + 1];
    float a[8];
#pragma unroll
    for (int j = 0; j < 8; j++) a[j] = 0.f;
    int base = e0;
    for (; base + 8 <= e1; base += 8) {
        int s0 = csr[base + slot];
        int s1 = csr[base + 4 + slot];
        bfrag v0 = *(const bfrag*)(hb + (size_t)s0 * HID + c16 * 8);
        bfrag v1 = *(const bfrag*)(hb + (size_t)s1 * HID + c16 * 8);
#pragma unroll
        for (int j = 0; j < 8; j++) {
            float t0 = b2f((ushort)v0[j]) * scv[j] + shv[j];
            float t1 = b2f((ushort)v1[j]) * scv[j] + shv[j];
            a[j] += fmaxf(t0, t0 * negk) + fmaxf(t1, t1 * negk);
        }
    }
    if (base + 4 <= e1) {
        int s0 = csr[base + slot];
        bfrag v0 = *(const bfrag*)(hb + (size_t)s0 * HID + c16 * 8);
#pragma unroll
        for (int j = 0; j < 8; j++) {
            float t0 = b2f((ushort)v0[j]) * scv[j] + shv[j];
            a[j] += fmaxf(t0, t0 * negk);
        }
        base += 4;
    }
    int rem = e1 - base;
    if (slot < rem) {
        int s0 = csr[base + slot];
        bfrag v0 = *(const bfrag*)(hb + (size_t)s0 * HID + c16 * 8);
#pragma unroll
        for (int j = 0; j < 8; j++) {
            float t0 = b2f((ushort)v0[j]) * scv[j] + shv[j];
            a[j] += fmaxf(t0, t0 * negk);
        }
    }
#pragma unroll
    for (int j = 0; j < 8; j++) {
        a[j] += __shfl_xor(a[j], 16);
        a[j] += __shfl_xor(a[j], 32);
    }
    if (slot == 0) {
        bfrag o;
#pragma unroll
        for (int j = 0; j < 8; j++) o[j] = (short)f2b(a[j]);
        *(bfrag*)(agg + (size_t)gw * HID + c16 * 8) = o;
    }
}

// ---- conv layer: 32 nodes/block, N-split x2 (r7/r9 proven form) -----------
__global__ __launch_bounds__(256) void k_conv(const ushort* __restrict__ agg,
                                              const ushort* __restrict__ hb,
                                              const ushort* __restrict__ relT,
                                              const ushort* __restrict__ rootT,
                                              const float* __restrict__ bias,
                                              const float* __restrict__ aff,
                                              float negk,
                                              float* __restrict__ bn_sh,
                                              ushort* __restrict__ h2) {
    __shared__ __align__(16) ushort tp[32 * 136];     // conv result (pre-residual)
    __shared__ __align__(16) ushort rtile[32 * 136];  // BN'd root rows
    __shared__ float lsum[256];
    __shared__ float lsc[128], lsh[128];
    int t = threadIdx.x;
    lsum[t] = 0.f;
    if (t < 128) { lsc[t] = aff[t]; lsh[t] = aff[128 + t]; }
    int lane = t & 63, wv = t >> 6;
    int ng = wv & 1, nh = wv >> 1;    // node-group, channel-half
    int l15 = lane & 15, q = lane >> 4;
    int node0 = blockIdx.x * 32 + ng * 16;
    int nA = min(node0 + l15, NN - 1);
    bfrag a1v[4], a2rv[4];
#pragma unroll
    for (int ks = 0; ks < 4; ks++) {
        a1v[ks] = *(const bfrag*)(agg + (size_t)nA * HID + ks * 32 + q * 8);
        a2rv[ks] = *(const bfrag*)(hb + (size_t)nA * HID + ks * 32 + q * 8);
    }
    __syncthreads();  // lsc/lsh + lsum init visible
    bfrag a2[4];
#pragma unroll
    for (int ks = 0; ks < 4; ks++) {
        float asc[8], ash[8];
        *(f4*)&asc[0] = *(const f4*)&lsc[ks * 32 + q * 8];
        *(f4*)&asc[4] = *(const f4*)&lsc[ks * 32 + q * 8 + 4];
        *(f4*)&ash[0] = *(const f4*)&lsh[ks * 32 + q * 8];
        *(f4*)&ash[4] = *(const f4*)&lsh[ks * 32 + q * 8 + 4];
#pragma unroll
        for (int j = 0; j < 8; j++) {
            float tt = b2f((ushort)a2rv[ks][j]) * asc[j] + ash[j];
            a2[ks][j] = (short)f2b(fmaxf(tt, tt * negk));
        }
        if (nh == 0)
            *(bfrag*)&rtile[(ng * 16 + l15) * 136 + ks * 32 + q * 8] = a2[ks];
    }
    f4 acc[4];
#pragma unroll
    for (int nt = 0; nt < 4; nt++) acc[nt] = (f4)0.0f;
#pragma unroll
    for (int ks = 0; ks < 4; ks++) {
#pragma unroll
        for (int nt = 0; nt < 4; nt++) {
            int ntg = nh * 4 + nt;
            bfrag b1 = *(const bfrag*)(relT + (ntg * 16 + l15) * HID + ks * 32 + q * 8);
            acc[nt] = __builtin_amdgcn_mfma_f32_16x16x32_bf16(a1v[ks], b1, acc[nt], 0, 0, 0);
            bfrag b2 = *(const bfrag*)(rootT + (ntg * 16 + l15) * HID + ks * 32 + q * 8);
            acc[nt] = __builtin_amdgcn_mfma_f32_16x16x32_bf16(a2[ks], b2, acc[nt], 0, 0, 0);
        }
    }
#pragma unroll
    for (int nt = 0; nt < 4; nt++) {
        int c = nh * 64 + nt * 16 + l15;
        float bs = bias[c];
#pragma unroll
        for (int r = 0; r < 4; r++)
            tp[(ng * 16 + q * 4 + r) * 136 + c] = f2b(acc[nt][r] + bs);
    }
    __syncthreads();
    // store path: thread = (row, 16-channel chunk)
    {
        int row = t >> 3, cb = (t & 7) * 16;
        int nr = blockIdx.x * 32 + row;
        if (nr < NN) {
            bfrag t0 = *(const bfrag*)&tp[row * 136 + cb];
            bfrag t1 = *(const bfrag*)&tp[row * 136 + cb + 8];
            bfrag r0 = *(const bfrag*)&rtile[row * 136 + cb];
            bfrag r1 = *(const bfrag*)&rtile[row * 136 + cb + 8];
            bfrag o0, o1;
#pragma unroll
            for (int j = 0; j < 8; j++) {
                o0[j] = (short)f2b(b2f((ushort)t0[j]) + b2f((ushort)r0[j]));
                o1[j] = (short)f2b(b2f((ushort)t1[j]) + b2f((ushort)r1[j]));
            }
            *(bfrag*)(h2 + (size_t)nr * HID + cb) = o0;
            *(bfrag*)(h2 + (size_t)nr * HID + cb + 8) = o1;
        }
    }
    // stats pass: wave wv covers rows wv*8..+8; lane covers channel pair (2l,2l+1)
    {
        float s0 = 0.f, s1 = 0.f, q0 = 0.f, q1 = 0.f;
        int c2 = lane * 2;
#pragma unroll
        for (int r = 0; r < 8; r++) {
            int row = wv * 8 + r;
            int nr = blockIdx.x * 32 + row;
            if (nr < NN) {
                unsigned tu = *(const unsigned*)&tp[row * 136 + c2];
                unsigned ru = *(const unsigned*)&rtile[row * 136 + c2];
                float v0 = b2f((ushort)(tu & 0xffffu)) + b2f((ushort)(ru & 0xffffu));
                float v1 = b2f((ushort)(tu >> 16)) + b2f((ushort)(ru >> 16));
                s0 += v0; s1 += v1; q0 += v0 * v0; q1 += v1 * v1;
            }
        }
        atomicAdd(&lsum[c2], s0);
        atomicAdd(&lsum[c2 + 1], s1);
        atomicAdd(&lsum[128 + c2], q0);
        atomicAdd(&lsum[128 + c2 + 1], q1);
    }
    __syncthreads();
    atomicAdd(&bn_sh[(blockIdx.x & 63) * 256 + t], lsum[t]);
}

// ---- reduce shards + compute next-layer affine (sc, sh) -------------------
__global__ void k_bnfin(const float* __restrict__ bn_sh, const float* __restrict__ gamma,
                        const float* __restrict__ beta, float* __restrict__ aff_out) {
    int t = threadIdx.x;  // 128 = channel
    float s = 0.f, s2 = 0.f;
#pragma unroll 8
    for (int k = 0; k < 64; k++) {
        s += bn_sh[k * 256 + t];
        s2 += bn_sh[k * 256 + 128 + t];
    }
    float mean = s * (1.0f / NN);
    float var = s2 * (1.0f / NN) - mean * mean;
    float sc = gamma[t] * rsqrtf(var + BN_EPS);
    aff_out[t] = sc;
    aff_out[128 + t] = beta[t] - mean * sc;
}

// ---- final conv 128->64: 32 nodes/block, N-split x2, fused add-pool -------
__global__ __launch_bounds__(256) void k_final(const ushort* __restrict__ agg,
                                               const ushort* __restrict__ hb,
                                               const ushort* __restrict__ relT,
                                               const ushort* __restrict__ rootT,
                                               const float* __restrict__ bias,
                                               const float* __restrict__ aff,
                                               const int* __restrict__ batch,
                                               float* __restrict__ out) {
    __shared__ __align__(16) float tpf[32 * 68];
    __shared__ float lsc[128], lsh[128];
    __shared__ int bt[32];
    int t = threadIdx.x;
    if (t < 128) { lsc[t] = aff[t]; lsh[t] = aff[128 + t]; }
    if (t < 32) {
        int n = blockIdx.x * 32 + t;
        bt[t] = (n < NN) ? batch[n] : -1;
    }
    int lane = t & 63, wv = t >> 6;
    int ng = wv & 1, nh = wv >> 1;
    int l15 = lane & 15, q = lane >> 4;
    int node0 = blockIdx.x * 32 + ng * 16;
    int nA = min(node0 + l15, NN - 1);
    bfrag a1v[4], a2rv[4];
#pragma unroll
    for (int ks = 0; ks < 4; ks++) {
        a1v[ks] = *(const bfrag*)(agg + (size_t)nA * HID + ks * 32 + q * 8);
        a2rv[ks] = *(const bfrag*)(hb + (size_t)nA * HID + ks * 32 + q * 8);
    }
    __syncthreads();
    f4 acc[2];
    acc[0] = (f4)0.0f; acc[1] = (f4)0.0f;
#pragma unroll
    for (int ks = 0; ks < 4; ks++) {
        float asc[8], ash[8];
        *(f4*)&asc[0] = *(const f4*)&lsc[ks * 32 + q * 8];
        *(f4*)&asc[4] = *(const f4*)&lsc[ks * 32 + q * 8 + 4];
        *(f4*)&ash[0] = *(const f4*)&lsh[ks * 32 + q * 8];
        *(f4*)&ash[4] = *(const f4*)&lsh[ks * 32 + q * 8 + 4];
        bfrag a2;
#pragma unroll
        for (int j = 0; j < 8; j++) {
            float tt = b2f((ushort)a2rv[ks][j]) * asc[j] + ash[j];
            a2[j] = (short)f2b(fmaxf(tt, 0.0f));
        }
#pragma unroll
        for (int nt = 0; nt < 2; nt++) {
            int ntg = nh * 2 + nt;
            bfrag b1 = *(const bfrag*)(relT + (ntg * 16 + l15) * HID + ks * 32 + q * 8);
            acc[nt] = __builtin_amdgcn_mfma_f32_16x16x32_bf16(a1v[ks], b1, acc[nt], 0, 0, 0);
            bfrag b2 = *(const bfrag*)(rootT + (ntg * 16 + l15) * HID + ks * 32 + q * 8);
            acc[nt] = __builtin_amdgcn_mfma_f32_16x16x32_bf16(a2, b2, acc[nt], 0, 0, 0);
        }
    }
#pragma unroll
    for (int nt = 0; nt < 2; nt++) {
        int c = nh * 32 + nt * 16 + l15;
        float bs = bias[c];
#pragma unroll
        for (int r = 0; r < 4; r++)
            tpf[(ng * 16 + q * 4 + r) * 68 + c] = acc[nt][r] + bs;
    }
    __syncthreads();
    // fused global_add_pool: 4 groups x 8 nodes, run-segmented
    int c = t & 63, grp = t >> 6;
    int g = bt[grp * 8];
    if (g >= 0) {
        float pacc = 0.f;
#pragma unroll
        for (int r = 0; r < 8; r++) {
            int b = bt[grp * 8 + r];
            if (b < 0) break;
            float v = tpf[(grp * 8 + r) * 68 + c];
            if (b != g) { atomicAdd(&out[g * OUTC + c], pacc); pacc = 0.f; g = b; }
            pacc += v;
        }
        atomicAdd(&out[g * OUTC + c], pacc);
    }
}

extern "C" void kernel_launch(void* const* d_in, const int* in_sizes, int n_in,
                              void* d_out, int out_size, void* d_ws, size_t ws_size,
                              hipStream_t stream) {
    const float* x      = (const float*)d_in[0];
    const int*   ei     = (const int*)d_in[1];
    const int*   batch  = (const int*)d_in[2];
    const float* lin_w  = (const float*)d_in[3];
    const float* lin_b  = (const float*)d_in[4];
    const float* rel_w  = (const float*)d_in[5];
    const float* root_w = (const float*)d_in[6];
    const float* conv_b = (const float*)d_in[7];
    const float* bn_g   = (const float*)d_in[8];
    const float* bn_b   = (const float*)d_in[9];
    const float* rel_l  = (const float*)d_in[10];
    const float* root_l = (const float*)d_in[11];
    const float* b_l    = (const float*)d_in[12];
    float* out = (float*)d_out;

    char* w = (char*)d_ws;
    ushort* h    = (ushort*)w;   w += (size_t)NN * HID * 2;   // 12.8 MB bf16
    ushort* h2   = (ushort*)w;   w += (size_t)NN * HID * 2;   // 12.8 MB bf16
    ushort* agg  = (ushort*)w;   w += (size_t)NN * HID * 2;   // 12.8 MB bf16
    unsigned* epk= (unsigned*)w; w += (size_t)NE * 4;         // 3.2 MB
    ushort* csr  = (ushort*)w;   w += (size_t)NE * 2;         // 1.6 MB
    int* p_hist  = (int*)w;      w += NPB * NBKT * 4;
    int* bstart  = (int*)w;      w += 800;
    int* btot    = (int*)w;      w += 800;
    int* offs    = (int*)w;      w += 200064;
    float* aff   = (float*)w;    w += 4 * 256 * 4;            // per-layer (sc,sh)
    float* bn_sh = (float*)w;    w += NLAY * 64 * 256 * 4;    // 192 KB shards
    ushort* wT   = (ushort*)w;   w += 131072 * 2;

    // merged: prep (512 blocks) | part1 (256 blocks)
    k_init<<<768, 256, 0, stream>>>(lin_w, rel_w, root_w, rel_l, root_l, wT,
                                    aff, bn_sh, out, ei, p_hist);
    // merged: lin (782 blocks) | part2a (196 blocks)
    k_linscan<<<LIN_BLOCKS + NBKT, 256, 0, stream>>>(x, wT, lin_b, h, p_hist, btot);
    k_part2b<<<1, 256, 0, stream>>>(btot, bstart, offs);
    k_part3<<<NPB, 256, 0, stream>>>(ei, p_hist, bstart, epk);
    k_csr<<<NBKT, 256, 0, stream>>>(epk, bstart, csr, offs);

    int conv_blocks = (NN + 31) / 32;  // 1563
    ushort* hb = h;
    ushort* ho = h2;
    for (int i = 0; i < NLAY; i++) {
        float negk = (i == 0) ? 1.0f : 0.0f;
        k_agg<<<(NN + 3) / 4, 256, 0, stream>>>(hb, offs, csr, aff + i * 256, negk, agg);
        k_conv<<<conv_blocks, 256, 0, stream>>>(agg, hb,
                                                wT + 16384 + i * 16384,
                                                wT + 65536 + i * 16384,
                                                conv_b + i * HID,
                                                aff + i * 256, negk,
                                                bn_sh + i * 64 * 256, ho);
        k_bnfin<<<1, 128, 0, stream>>>(bn_sh + i * 64 * 256, bn_g + i * HID,
                                       bn_b + i * HID, aff + (i + 1) * 256);
        ushort* tmp = hb; hb = ho; ho = tmp;
    }

    k_agg<<<(NN + 3) / 4, 256, 0, stream>>>(hb, offs, csr, aff + 3 * 256, 0.0f, agg);
    k_final<<<conv_blocks, 256, 0, stream>>>(agg, hb, wT + 114688, wT + 122880, b_l,
                                             aff + 3 * 256, batch, out);
}